// Round 3
// baseline (265.494 us; speedup 1.0000x reference)
//
#include <hip/hip_runtime.h>
#include <hip/hip_bf16.h>

#define NB 4
#define CDIM 128
#define NPIX 1600
#define WIMG 40
#define HCH 256
#define NHEADS 8
#define KDQ 8
#define HDV 16
#define EPSV 1e-3f
#define SCALEV 0.35355339059327373f
#define NT 400

// ---------------- K1: qkv = BN(conv1x1(x)); q channels pre-scaled by SCALE ----------------
__global__ __launch_bounds__(256) void k_qkv(
    const float* __restrict__ x, const float* __restrict__ w,
    const float* __restrict__ gg, const float* __restrict__ bb,
    const float* __restrict__ mm, const float* __restrict__ vv,
    float* __restrict__ qkv)
{
  const int pblk = blockIdx.x % 7;
  const int ct   = (blockIdx.x / 7) % (HCH / 8);
  const int b    = blockIdx.x / (7 * (HCH / 8));
  const int tid  = threadIdx.x;

  __shared__ float wl[8][CDIM];
  for (int i = tid; i < 8 * CDIM; i += 256)
    wl[i >> 7][i & 127] = w[(ct * 8 + (i >> 7)) * CDIM + (i & 127)];
  __syncthreads();

  const int p = pblk * 256 + tid;
  if (p >= NPIX) return;

  const float* xb = x + (size_t)b * CDIM * NPIX + p;
  float acc[8] = {0.f, 0.f, 0.f, 0.f, 0.f, 0.f, 0.f, 0.f};
  for (int ci = 0; ci < CDIM; ++ci) {
    const float xv = xb[(size_t)ci * NPIX];
#pragma unroll
    for (int j = 0; j < 8; ++j) acc[j] += wl[j][ci] * xv;
  }
#pragma unroll
  for (int j = 0; j < 8; ++j) {
    const int c = ct * 8 + j;
    const float sc = gg[c] * rsqrtf(vv[c] + EPSV);
    const float bi = bb[c] - mm[c] * sc;
    float o = acc[j] * sc + bi;
    if ((c & 31) < KDQ) o *= SCALEV;   // pre-scale q
    qkv[((size_t)b * HCH + c) * NPIX + p] = o;
  }
}

// ---------------- K2: pe = BN(dwconv3x3(v)) ----------------
__global__ __launch_bounds__(256) void k_pe(
    const float* __restrict__ qkv, const float* __restrict__ w,
    const float* __restrict__ gg, const float* __restrict__ bb,
    const float* __restrict__ mm, const float* __restrict__ vv,
    float* __restrict__ pe)
{
  const int idx = blockIdx.x * 256 + threadIdx.x;
  if (idx >= NB * CDIM * NPIX) return;
  const int p  = idx % NPIX;
  const int vc = (idx / NPIX) % CDIM;
  const int b  = idx / (NPIX * CDIM);
  const int yy = p / WIMG, xx = p % WIMG;
  // v channel vc lives at qkv channel (vc/16)*32 + 16 + vc%16
  const int qc = (vc >> 4) * 32 + 16 + (vc & 15);
  const float* vb = qkv + ((size_t)b * HCH + qc) * NPIX;
  float acc = 0.f;
#pragma unroll
  for (int dy = -1; dy <= 1; ++dy)
#pragma unroll
    for (int dx = -1; dx <= 1; ++dx) {
      const int y2 = yy + dy, x2 = xx + dx;
      if ((unsigned)y2 < (unsigned)WIMG && (unsigned)x2 < (unsigned)WIMG)
        acc += w[vc * 9 + (dy + 1) * 3 + (dx + 1)] * vb[y2 * WIMG + x2];
    }
  const float sc = gg[vc] * rsqrtf(vv[vc] + EPSV);
  const float bi = bb[vc] - mm[vc] * sc;
  pe[idx] = acc * sc + bi;
}

// ---------------- K3: fused attention (no-max softmax, single pass) ----------------
// block: one (b,h,64-query chunk); 256 thr = 64 queries x 4 key-splits (interleaved n)
__global__ __launch_bounds__(256) void k_attn(
    const float* __restrict__ qkv, float* __restrict__ attno)
{
  const int qc = blockIdx.x % 25;
  const int h  = (blockIdx.x / 25) % NHEADS;
  const int b  = blockIdx.x / (25 * NHEADS);
  const int tid = threadIdx.x;
  const int qi = tid >> 2;   // 0..63
  const int sp = tid & 3;    // key split
  const int m  = qc * 64 + qi;

  __shared__ float klds[NT][KDQ];
  __shared__ float vlds[NT][HDV];

  const float* qkb = qkv + (size_t)b * HCH * NPIX + (size_t)h * 32 * NPIX;

  float qv[KDQ];
#pragma unroll
  for (int kk = 0; kk < KDQ; ++kk) qv[kk] = qkb[(size_t)kk * NPIX + m];

  float l = 0.f;
  float acc[HDV];
#pragma unroll
  for (int d = 0; d < HDV; ++d) acc[d] = 0.f;

  for (int t = 0; t < NPIX / NT; ++t) {
    __syncthreads();
    for (int i = tid; i < NT * KDQ; i += 256) {
      const int nl = i >> 3, kk = i & 7;
      klds[nl][kk] = qkb[(size_t)(KDQ + kk) * NPIX + t * NT + nl];
    }
    for (int i = tid; i < NT * HDV; i += 256) {
      const int nl = i >> 4, dd = i & 15;
      vlds[nl][dd] = qkb[(size_t)(2 * KDQ + dd) * NPIX + t * NT + nl];
    }
    __syncthreads();
    for (int i = sp; i < NT; i += 4) {
      const float4 k0 = *reinterpret_cast<const float4*>(&klds[i][0]);
      const float4 k1 = *reinterpret_cast<const float4*>(&klds[i][4]);
      float s0 = qv[0] * k0.x + qv[1] * k0.y;
      float s1 = qv[2] * k0.z + qv[3] * k0.w;
      s0 += qv[4] * k1.x; s1 += qv[5] * k1.y;
      s0 += qv[6] * k1.z; s1 += qv[7] * k1.w;
      const float pr = __expf(s0 + s1);   // scores are O(1): safe without max-sub
      l += pr;
      const float4 v0 = *reinterpret_cast<const float4*>(&vlds[i][0]);
      const float4 v1 = *reinterpret_cast<const float4*>(&vlds[i][4]);
      const float4 v2 = *reinterpret_cast<const float4*>(&vlds[i][8]);
      const float4 v3 = *reinterpret_cast<const float4*>(&vlds[i][12]);
      acc[0]  += pr * v0.x; acc[1]  += pr * v0.y; acc[2]  += pr * v0.z; acc[3]  += pr * v0.w;
      acc[4]  += pr * v1.x; acc[5]  += pr * v1.y; acc[6]  += pr * v1.z; acc[7]  += pr * v1.w;
      acc[8]  += pr * v2.x; acc[9]  += pr * v2.y; acc[10] += pr * v2.z; acc[11] += pr * v2.w;
      acc[12] += pr * v3.x; acc[13] += pr * v3.y; acc[14] += pr * v3.z; acc[15] += pr * v3.w;
    }
  }

  // combine the 4 key-splits (lanes 4q..4q+3)
#pragma unroll
  for (int d = 0; d < HDV; ++d) {
    acc[d] += __shfl_xor(acc[d], 1);
    acc[d] += __shfl_xor(acc[d], 2);
  }
  l += __shfl_xor(l, 1);
  l += __shfl_xor(l, 2);
  const float rl = 1.f / l;

  float* ob = attno + ((size_t)b * CDIM + h * HDV) * NPIX + m;
#pragma unroll
  for (int j = 0; j < 4; ++j)
    ob[(size_t)(sp * 4 + j) * NPIX] = acc[sp * 4 + j] * rl;
}

// ---------------- K4: y = BN(conv1x1(attno + pe)) -> f32 out ----------------
__global__ __launch_bounds__(256) void k_proj(
    const float* __restrict__ attno, const float* __restrict__ pe,
    const float* __restrict__ w,
    const float* __restrict__ gg, const float* __restrict__ bb,
    const float* __restrict__ mm, const float* __restrict__ vv,
    float* __restrict__ out)
{
  const int pblk = blockIdx.x % 7;
  const int ct   = (blockIdx.x / 7) % (CDIM / 8);
  const int b    = blockIdx.x / (7 * (CDIM / 8));
  const int tid  = threadIdx.x;

  __shared__ float wl[8][CDIM];
  for (int i = tid; i < 8 * CDIM; i += 256)
    wl[i >> 7][i & 127] = w[(ct * 8 + (i >> 7)) * CDIM + (i & 127)];
  __syncthreads();

  const int p = pblk * 256 + tid;
  if (p >= NPIX) return;

  const float* ab = attno + (size_t)b * CDIM * NPIX + p;
  const float* pb = pe    + (size_t)b * CDIM * NPIX + p;
  float acc[8] = {0.f, 0.f, 0.f, 0.f, 0.f, 0.f, 0.f, 0.f};
  for (int ci = 0; ci < CDIM; ++ci) {
    const float xv = ab[(size_t)ci * NPIX] + pb[(size_t)ci * NPIX];
#pragma unroll
    for (int j = 0; j < 8; ++j) acc[j] += wl[j][ci] * xv;
  }
#pragma unroll
  for (int j = 0; j < 8; ++j) {
    const int c = ct * 8 + j;
    const float sc = gg[c] * rsqrtf(vv[c] + EPSV);
    const float bi = bb[c] - mm[c] * sc;
    out[((size_t)b * CDIM + c) * NPIX + p] = acc[j] * sc + bi;
  }
}

extern "C" void kernel_launch(void* const* d_in, const int* in_sizes, int n_in,
                              void* d_out, int out_size, void* d_ws, size_t ws_size,
                              hipStream_t stream)
{
  const float* x      = (const float*)d_in[0];
  const float* qkv_w  = (const float*)d_in[1];
  const float* qkv_g  = (const float*)d_in[2];
  const float* qkv_b  = (const float*)d_in[3];
  const float* qkv_m  = (const float*)d_in[4];
  const float* qkv_v  = (const float*)d_in[5];
  const float* pe_w   = (const float*)d_in[6];
  const float* pe_g   = (const float*)d_in[7];
  const float* pe_b   = (const float*)d_in[8];
  const float* pe_m   = (const float*)d_in[9];
  const float* pe_v   = (const float*)d_in[10];
  const float* proj_w = (const float*)d_in[11];
  const float* proj_g = (const float*)d_in[12];
  const float* proj_b = (const float*)d_in[13];
  const float* proj_m = (const float*)d_in[14];
  const float* proj_v = (const float*)d_in[15];

  float* ws   = (float*)d_ws;
  float* qkvb = ws;                                   // 4*256*1600 = 1,638,400 f
  float* peb  = qkvb + (size_t)NB * HCH * NPIX;       //   819,200 f
  float* atb  = peb  + (size_t)NB * CDIM * NPIX;      //   819,200 f

  k_qkv<<<dim3(NB * (HCH / 8) * 7), 256, 0, stream>>>(
      x, qkv_w, qkv_g, qkv_b, qkv_m, qkv_v, qkvb);
  k_pe<<<dim3((NB * CDIM * NPIX + 255) / 256), 256, 0, stream>>>(
      qkvb, pe_w, pe_g, pe_b, pe_m, pe_v, peb);
  k_attn<<<dim3(NB * NHEADS * 25), 256, 0, stream>>>(qkvb, atb);
  k_proj<<<dim3(NB * (CDIM / 8) * 7), 256, 0, stream>>>(
      atb, peb, proj_w, proj_g, proj_b, proj_m, proj_v, (float*)d_out);
}

// Round 6
// 188.633 us; speedup vs baseline: 1.4075x; 1.4075x over previous
//
#include <hip/hip_runtime.h>
#include <hip/hip_bf16.h>

#define NB 4
#define CDIM 128
#define NPIX 1600
#define WIMG 40
#define HCH 256
#define NHEADS 8
#define KDQ 8
#define HDV 16
#define EPSV 1e-3f
#define SCALEV 0.35355339059327373f
#define KT 320
#define KLP 24          // K-LDS row pad (u16) for 32B rows
#define VTP (KT + 8)

typedef unsigned short u16;
typedef float f32x4 __attribute__((ext_vector_type(4)));
typedef __bf16 bf16x8 __attribute__((ext_vector_type(8)));

union U16B { uint4 u; bf16x8 v; };

__device__ __forceinline__ u16 f2bf(float f) {   // RNE float->bf16 bits
  unsigned u = __float_as_uint(f);
  return (u16)((u + 0x7FFFu + ((u >> 16) & 1u)) >> 16);
}
__device__ __forceinline__ float bf2f(u16 b) {
  return __uint_as_float(((unsigned)b) << 16);
}
__device__ __forceinline__ unsigned cvt_pk_bf16(float lo, float hi) {
  unsigned r;
  asm("v_cvt_pk_bf16_f32 %0, %1, %2" : "=v"(r) : "v"(lo), "v"(hi));
  return r;
}

// ---------------- K1: qkv = BN(conv1x1(x)) ----------------
// Emits q/k as hi+lo bf16 split rows ([n][16]: 8 hi then 8 lo), v-transposed
// bf16 ([d][n]) and fp32 v (for pe). q pre-scaled by SCALE.
__global__ __launch_bounds__(256) void k_qkv(
    const float* __restrict__ x, const float* __restrict__ w,
    const float* __restrict__ gg, const float* __restrict__ bb,
    const float* __restrict__ mm, const float* __restrict__ vv,
    float* __restrict__ vf32, u16* __restrict__ qbf,
    u16* __restrict__ kbf, u16* __restrict__ vtbf)
{
  const int pblk = blockIdx.x % 7;
  const int ct   = (blockIdx.x / 7) % (HCH / 8);
  const int b    = blockIdx.x / (7 * (HCH / 8));
  const int tid  = threadIdx.x;

  __shared__ float wl[8][CDIM];
  for (int i = tid; i < 8 * CDIM; i += 256)
    wl[i >> 7][i & 127] = w[(ct * 8 + (i >> 7)) * CDIM + (i & 127)];
  __syncthreads();

  const int p = pblk * 256 + tid;
  if (p >= NPIX) return;

  const float* xb = x + (size_t)b * CDIM * NPIX + p;
  float acc[8] = {0.f, 0.f, 0.f, 0.f, 0.f, 0.f, 0.f, 0.f};
#pragma unroll 4
  for (int ci = 0; ci < CDIM; ++ci) {
    const float xv = xb[(size_t)ci * NPIX];
#pragma unroll
    for (int j = 0; j < 8; ++j) acc[j] += wl[j][ci] * xv;
  }

  const int grp = ct & 3;   // 0=q(kd0-7) 1=k(kd0-7) 2=v(d0-7) 3=v(d8-15)
  const int h   = ct >> 2;
  float o[8];
#pragma unroll
  for (int j = 0; j < 8; ++j) {
    const int c = ct * 8 + j;
    const float sc = gg[c] * rsqrtf(vv[c] + EPSV);
    const float bi = bb[c] - mm[c] * sc;
    o[j] = acc[j] * sc + bi;
    if (grp == 0) o[j] *= SCALEV;
  }

  if (grp <= 1) {
    u16 hb[8], lb[8];
#pragma unroll
    for (int j = 0; j < 8; ++j) {
      hb[j] = f2bf(o[j]);
      lb[j] = f2bf(o[j] - bf2f(hb[j]));
    }
    uint4 H, L;
    H.x = hb[0] | ((unsigned)hb[1] << 16);
    H.y = hb[2] | ((unsigned)hb[3] << 16);
    H.z = hb[4] | ((unsigned)hb[5] << 16);
    H.w = hb[6] | ((unsigned)hb[7] << 16);
    L.x = lb[0] | ((unsigned)lb[1] << 16);
    L.y = lb[2] | ((unsigned)lb[3] << 16);
    L.z = lb[4] | ((unsigned)lb[5] << 16);
    L.w = lb[6] | ((unsigned)lb[7] << 16);
    u16* dst = (grp == 0) ? qbf : kbf;
    const size_t base = ((size_t)(b * NHEADS + h) * NPIX + p) * 16;
    *(uint4*)&dst[base]     = H;
    *(uint4*)&dst[base + 8] = L;
  } else {
    const int d0 = (grp == 2) ? 0 : 8;
#pragma unroll
    for (int j = 0; j < 8; ++j) {
      vtbf[((size_t)(b * NHEADS + h) * HDV + d0 + j) * NPIX + p] = f2bf(o[j]);
      vf32[((size_t)b * CDIM + h * HDV + d0 + j) * NPIX + p] = o[j];
    }
  }
}

// ---------------- K2: pe = BN(dwconv3x3(v)) ----------------
__global__ __launch_bounds__(256) void k_pe(
    const float* __restrict__ vf32, const float* __restrict__ w,
    const float* __restrict__ gg, const float* __restrict__ bb,
    const float* __restrict__ mm, const float* __restrict__ vv,
    float* __restrict__ pe)
{
  const int idx = blockIdx.x * 256 + threadIdx.x;
  if (idx >= NB * CDIM * NPIX) return;
  const int p  = idx % NPIX;
  const int vc = (idx / NPIX) % CDIM;
  const int b  = idx / (NPIX * CDIM);
  const int yy = p / WIMG, xx = p % WIMG;
  const float* vb = vf32 + ((size_t)b * CDIM + vc) * NPIX;
  float acc = 0.f;
#pragma unroll
  for (int dy = -1; dy <= 1; ++dy)
#pragma unroll
    for (int dx = -1; dx <= 1; ++dx) {
      const int y2 = yy + dy, x2 = xx + dx;
      if ((unsigned)y2 < (unsigned)WIMG && (unsigned)x2 < (unsigned)WIMG)
        acc += w[vc * 9 + (dy + 1) * 3 + (dx + 1)] * vb[y2 * WIMG + x2];
    }
  const float sc = gg[vc] * rsqrtf(vv[vc] + EPSV);
  const float bi = bb[vc] - mm[vc] * sc;
  pe[idx] = acc * sc + bi;
}

// ---------------- K3: MFMA attention (hi/lo split-precision QK^T) ----------------
// block = (b,h, 64-query tile); 4 waves x 16 queries.
// QK^T: A-groups = [k_hi,k_hi,k_lo,k_lo], B-groups = [q_hi,q_lo,q_hi,q_lo]
//  -> one MFMA yields full-precision scores (hi*hi + hi*lo + lo*hi + lo*lo).
// P (C-layout) -> B-frag layout via cvt_pk + 8 ds_bpermute; lsum from the
// QUANTIZED P so numerator/denominator weights are identical.
// PV: out[d][q] = mfma(A=Vt, B=P) accumulated over all 1600 keys.
__global__ __launch_bounds__(256) void k_attn(
    const u16* __restrict__ qbf, const u16* __restrict__ kbf,
    const u16* __restrict__ vtbf, float* __restrict__ attno)
{
  const int bh   = blockIdx.x & 31;
  const int qblk = blockIdx.x >> 5;          // 0..24
  const int b = bh >> 3, h = bh & 7;
  const int tid = threadIdx.x;
  const int lane = tid & 63, wid = tid >> 6;
  const int qloc = lane & 15, g = lane >> 4;

  __shared__ __align__(16) u16 Klds[KT][KLP];     // [key][hi0-7 lo0-7 pad]
  __shared__ __align__(16) u16 Vtlds[HDV][VTP];   // [d][key], padded rows

  // Q fragment (B-operand): group g holds q_hi (g even) or q_lo (g odd).
  const int qglob = qblk * 64 + wid * 16 + qloc;
  U16B qf;
  qf.u = *(const uint4*)&qbf[((size_t)bh * NPIX + qglob) * 16 + (g & 1) * 8];

  f32x4 c3 = {0.f, 0.f, 0.f, 0.f};
  float lsum = 0.f;
  const int idx0 = (((g & 1) << 5) | qloc) << 2;  // bpermute byte index
  const int idx1 = idx0 + 64;                     // +16 lanes
  const bool selA = (g < 2);
  const f32x4 zf = {0.f, 0.f, 0.f, 0.f};
  const int ksel = (g >> 1) * 8;                  // K-frag hi/lo select

  for (int kt = 0; kt < NPIX / KT; ++kt) {
    const int kb0 = kt * KT;
    __syncthreads();
    for (int i = tid; i < KT * 2; i += 256) {
      const int r = i >> 1, hf = (i & 1) * 8;
      *(uint4*)&Klds[r][hf] =
          *(const uint4*)&kbf[((size_t)bh * NPIX + kb0 + r) * 16 + hf];
    }
    for (int c = tid; c < HDV * (KT / 8); c += 256) {
      const int d = c / (KT / 8), n0 = (c % (KT / 8)) * 8;
      *(uint4*)&Vtlds[d][n0] =
          *(const uint4*)&vtbf[((size_t)bh * HDV + d) * NPIX + kb0 + n0];
    }
    __syncthreads();

    for (int ks = 0; ks < KT / 32; ++ks) {
      // K fragments (A-operand): row m=qloc's hi (g<2) or lo (g>=2) half.
      U16B kfA, kfB;
      kfA.u = *(const uint4*)&Klds[ks * 32 + qloc][ksel];
      kfB.u = *(const uint4*)&Klds[ks * 32 + 16 + qloc][ksel];
      // S^T tiles: C[row=key][col=query]; lane holds keys g*4+r, query qloc.
      f32x4 cA = __builtin_amdgcn_mfma_f32_16x16x32_bf16(kfA.v, qf.v, zf, 0, 0, 0);
      f32x4 cB = __builtin_amdgcn_mfma_f32_16x16x32_bf16(kfB.v, qf.v, zf, 0, 0, 0);

      const unsigned pkA0 = cvt_pk_bf16(__expf(cA[0]), __expf(cA[1]));
      const unsigned pkA1 = cvt_pk_bf16(__expf(cA[2]), __expf(cA[3]));
      const unsigned pkB0 = cvt_pk_bf16(__expf(cB[0]), __expf(cB[1]));
      const unsigned pkB1 = cvt_pk_bf16(__expf(cB[2]), __expf(cB[3]));

      // Rearrange P (C-layout) -> B-frag layout: lane needs keys 8g..8g+7
      // for its query.
      const int a0 = __builtin_amdgcn_ds_bpermute(idx0, (int)pkA0);
      const int b0 = __builtin_amdgcn_ds_bpermute(idx0, (int)pkB0);
      const int a1 = __builtin_amdgcn_ds_bpermute(idx0, (int)pkA1);
      const int b1 = __builtin_amdgcn_ds_bpermute(idx0, (int)pkB1);
      const int a2 = __builtin_amdgcn_ds_bpermute(idx1, (int)pkA0);
      const int b2 = __builtin_amdgcn_ds_bpermute(idx1, (int)pkB0);
      const int a3 = __builtin_amdgcn_ds_bpermute(idx1, (int)pkA1);
      const int b3 = __builtin_amdgcn_ds_bpermute(idx1, (int)pkB1);
      U16B pf;
      pf.u.x = (unsigned)(selA ? a0 : b0);
      pf.u.y = (unsigned)(selA ? a1 : b1);
      pf.u.z = (unsigned)(selA ? a2 : b2);
      pf.u.w = (unsigned)(selA ? a3 : b3);

      // lsum from the QUANTIZED P (this lane's 8 keys for its query).
      lsum += __uint_as_float(pf.u.x << 16) + __uint_as_float(pf.u.x & 0xFFFF0000u)
            + __uint_as_float(pf.u.y << 16) + __uint_as_float(pf.u.y & 0xFFFF0000u)
            + __uint_as_float(pf.u.z << 16) + __uint_as_float(pf.u.z & 0xFFFF0000u)
            + __uint_as_float(pf.u.w << 16) + __uint_as_float(pf.u.w & 0xFFFF0000u);

      // V^T fragment (A-operand): Vt[d=qloc][keys 8g..8g+7]
      U16B vf4;
      vf4.u = *(const uint4*)&Vtlds[qloc][ks * 32 + g * 8];

      c3 = __builtin_amdgcn_mfma_f32_16x16x32_bf16(vf4.v, pf.v, c3, 0, 0, 0);
    }
  }

  lsum += __shfl_xor(lsum, 16);
  lsum += __shfl_xor(lsum, 32);
  const float rl = 1.f / lsum;

  // C3[row=d][col=q]: lane holds d = g*4+r, q = qloc. Coalesced row writes.
  float* ob = attno + ((size_t)b * CDIM + h * HDV) * NPIX + qblk * 64 + wid * 16 + qloc;
#pragma unroll
  for (int r = 0; r < 4; ++r)
    ob[(size_t)(g * 4 + r) * NPIX] = c3[r] * rl;
}

// ---------------- K4: y = BN(conv1x1(attno + pe)) -> f32 out ----------------
__global__ __launch_bounds__(256) void k_proj(
    const float* __restrict__ attno, const float* __restrict__ pe,
    const float* __restrict__ w,
    const float* __restrict__ gg, const float* __restrict__ bb,
    const float* __restrict__ mm, const float* __restrict__ vv,
    float* __restrict__ out)
{
  const int pblk = blockIdx.x % 7;
  const int ct   = (blockIdx.x / 7) % (CDIM / 8);
  const int b    = blockIdx.x / (7 * (CDIM / 8));
  const int tid  = threadIdx.x;

  __shared__ float wl[8][CDIM];
  for (int i = tid; i < 8 * CDIM; i += 256)
    wl[i >> 7][i & 127] = w[(ct * 8 + (i >> 7)) * CDIM + (i & 127)];
  __syncthreads();

  const int p = pblk * 256 + tid;
  if (p >= NPIX) return;

  const float* ab = attno + (size_t)b * CDIM * NPIX + p;
  const float* pb = pe    + (size_t)b * CDIM * NPIX + p;
  float acc[8] = {0.f, 0.f, 0.f, 0.f, 0.f, 0.f, 0.f, 0.f};
#pragma unroll 4
  for (int ci = 0; ci < CDIM; ++ci) {
    const float xv = ab[(size_t)ci * NPIX] + pb[(size_t)ci * NPIX];
#pragma unroll
    for (int j = 0; j < 8; ++j) acc[j] += wl[j][ci] * xv;
  }
#pragma unroll
  for (int j = 0; j < 8; ++j) {
    const int c = ct * 8 + j;
    const float sc = gg[c] * rsqrtf(vv[c] + EPSV);
    const float bi = bb[c] - mm[c] * sc;
    out[((size_t)b * CDIM + c) * NPIX + p] = acc[j] * sc + bi;
  }
}

extern "C" void kernel_launch(void* const* d_in, const int* in_sizes, int n_in,
                              void* d_out, int out_size, void* d_ws, size_t ws_size,
                              hipStream_t stream)
{
  const float* x      = (const float*)d_in[0];
  const float* qkv_w  = (const float*)d_in[1];
  const float* qkv_g  = (const float*)d_in[2];
  const float* qkv_b  = (const float*)d_in[3];
  const float* qkv_m  = (const float*)d_in[4];
  const float* qkv_v  = (const float*)d_in[5];
  const float* pe_w   = (const float*)d_in[6];
  const float* pe_g   = (const float*)d_in[7];
  const float* pe_b   = (const float*)d_in[8];
  const float* pe_m   = (const float*)d_in[9];
  const float* pe_v   = (const float*)d_in[10];
  const float* proj_w = (const float*)d_in[11];
  const float* proj_g = (const float*)d_in[12];
  const float* proj_b = (const float*)d_in[13];
  const float* proj_m = (const float*)d_in[14];
  const float* proj_v = (const float*)d_in[15];

  float* ws   = (float*)d_ws;
  float* vf32 = ws;                                  // 819,200 f
  float* peb  = vf32 + (size_t)NB * CDIM * NPIX;     // 819,200 f
  float* atb  = peb  + (size_t)NB * CDIM * NPIX;     // 819,200 f
  u16*   qbf  = (u16*)(atb + (size_t)NB * CDIM * NPIX);        // 819,200 u16 (hi+lo)
  u16*   kbf  = qbf + (size_t)NB * NHEADS * NPIX * 16;         // 819,200 u16 (hi+lo)
  u16*   vtbf = kbf + (size_t)NB * NHEADS * NPIX * 16;         // 819,200 u16

  k_qkv<<<dim3(NB * (HCH / 8) * 7), 256, 0, stream>>>(
      x, qkv_w, qkv_g, qkv_b, qkv_m, qkv_v, vf32, qbf, kbf, vtbf);
  k_pe<<<dim3((NB * CDIM * NPIX + 255) / 256), 256, 0, stream>>>(
      vf32, pe_w, pe_g, pe_b, pe_m, pe_v, peb);
  k_attn<<<dim3(NB * NHEADS * 25), 256, 0, stream>>>(qbf, kbf, vtbf, atb);
  k_proj<<<dim3(NB * (CDIM / 8) * 7), 256, 0, stream>>>(
      atb, peb, proj_w, proj_g, proj_b, proj_m, proj_v, (float*)d_out);
}

// Round 7
// 153.155 us; speedup vs baseline: 1.7335x; 1.2316x over previous
//
#include <hip/hip_runtime.h>
#include <hip/hip_bf16.h>

#define NB 4
#define CDIM 128
#define NPIX 1600
#define WIMG 40
#define HCH 256
#define NHEADS 8
#define KDQ 8
#define HDV 16
#define EPSV 1e-3f
#define SCALEV 0.35355339059327373f
#define KT 320
#define KLP 24          // K-LDS row pad (u16) for 32B rows
#define VTP (KT + 8)

typedef unsigned short u16;
typedef float f32x4 __attribute__((ext_vector_type(4)));
typedef __bf16 bf16x8 __attribute__((ext_vector_type(8)));

union U16B { uint4 u; bf16x8 v; };

__device__ __forceinline__ u16 f2bf(float f) {   // RNE float->bf16 bits
  unsigned u = __float_as_uint(f);
  return (u16)((u + 0x7FFFu + ((u >> 16) & 1u)) >> 16);
}
__device__ __forceinline__ float bf2f(u16 b) {
  return __uint_as_float(((unsigned)b) << 16);
}
__device__ __forceinline__ unsigned cvt_pk_bf16(float lo, float hi) {
  unsigned r;
  asm("v_cvt_pk_bf16_f32 %0, %1, %2" : "=v"(r) : "v"(lo), "v"(hi));
  return r;
}

// ---------------- K1: qkv = BN(conv1x1(x)), split-K over ci ----------------
// 512 threads: half 0/1 each accumulate 64 ci, LDS-reduce, half 0 stores.
// Emits q/k as hi+lo bf16 split rows ([n][16]), v^T bf16 ([d][n]), fp32 v.
__global__ __launch_bounds__(512) void k_qkv(
    const float* __restrict__ x, const float* __restrict__ w,
    const float* __restrict__ gg, const float* __restrict__ bb,
    const float* __restrict__ mm, const float* __restrict__ vv,
    float* __restrict__ vf32, u16* __restrict__ qbf,
    u16* __restrict__ kbf, u16* __restrict__ vtbf)
{
  const int pblk = blockIdx.x % 7;
  const int ct   = (blockIdx.x / 7) % (HCH / 8);
  const int b    = blockIdx.x / (7 * (HCH / 8));
  const int tid  = threadIdx.x;
  const int half = tid >> 8;
  const int t    = tid & 255;

  __shared__ float wl[8][CDIM];
  __shared__ float red[256][8];
  for (int i = tid; i < 8 * CDIM; i += 512)
    wl[i >> 7][i & 127] = w[(ct * 8 + (i >> 7)) * CDIM + (i & 127)];
  __syncthreads();

  const int praw = pblk * 256 + t;
  const int p    = praw < NPIX ? praw : NPIX - 1;   // clamp (no early return)

  const float* xb = x + (size_t)b * CDIM * NPIX + p;
  float acc[8] = {0.f, 0.f, 0.f, 0.f, 0.f, 0.f, 0.f, 0.f};
  const int c0 = half * 64;
#pragma unroll 4
  for (int ci = c0; ci < c0 + 64; ++ci) {
    const float xv = xb[(size_t)ci * NPIX];
#pragma unroll
    for (int j = 0; j < 8; ++j) acc[j] += wl[j][ci] * xv;
  }

  if (half == 1) {
#pragma unroll
    for (int j = 0; j < 8; ++j) red[t][j] = acc[j];
  }
  __syncthreads();
  if (half == 1 || praw >= NPIX) return;
#pragma unroll
  for (int j = 0; j < 8; ++j) acc[j] += red[t][j];

  const int grp = ct & 3;   // 0=q(kd0-7) 1=k(kd0-7) 2=v(d0-7) 3=v(d8-15)
  const int h   = ct >> 2;
  float o[8];
#pragma unroll
  for (int j = 0; j < 8; ++j) {
    const int c = ct * 8 + j;
    const float sc = gg[c] * rsqrtf(vv[c] + EPSV);
    const float bi = bb[c] - mm[c] * sc;
    o[j] = acc[j] * sc + bi;
    if (grp == 0) o[j] *= SCALEV;
  }

  if (grp <= 1) {
    u16 hb[8], lb[8];
#pragma unroll
    for (int j = 0; j < 8; ++j) {
      hb[j] = f2bf(o[j]);
      lb[j] = f2bf(o[j] - bf2f(hb[j]));
    }
    uint4 H, L;
    H.x = hb[0] | ((unsigned)hb[1] << 16);
    H.y = hb[2] | ((unsigned)hb[3] << 16);
    H.z = hb[4] | ((unsigned)hb[5] << 16);
    H.w = hb[6] | ((unsigned)hb[7] << 16);
    L.x = lb[0] | ((unsigned)lb[1] << 16);
    L.y = lb[2] | ((unsigned)lb[3] << 16);
    L.z = lb[4] | ((unsigned)lb[5] << 16);
    L.w = lb[6] | ((unsigned)lb[7] << 16);
    u16* dst = (grp == 0) ? qbf : kbf;
    const size_t base = ((size_t)(b * NHEADS + h) * NPIX + p) * 16;
    *(uint4*)&dst[base]     = H;
    *(uint4*)&dst[base + 8] = L;
  } else {
    const int d0 = (grp == 2) ? 0 : 8;
#pragma unroll
    for (int j = 0; j < 8; ++j) {
      vtbf[((size_t)(b * NHEADS + h) * HDV + d0 + j) * NPIX + p] = f2bf(o[j]);
      vf32[((size_t)b * CDIM + h * HDV + d0 + j) * NPIX + p] = o[j];
    }
  }
}

// ---------------- K2: atb += BN(dwconv3x3(v))  (runs AFTER k_attn) ----------------
__global__ __launch_bounds__(256) void k_peadd(
    const float* __restrict__ vf32, const float* __restrict__ w,
    const float* __restrict__ gg, const float* __restrict__ bb,
    const float* __restrict__ mm, const float* __restrict__ vv,
    float* __restrict__ atb)
{
  const int idx = blockIdx.x * 256 + threadIdx.x;
  if (idx >= NB * CDIM * NPIX) return;
  const int p  = idx % NPIX;
  const int vc = (idx / NPIX) % CDIM;
  const int yy = p / WIMG, xx = p % WIMG;
  const float* vb = vf32 + (size_t)(idx - p);   // same (b,vc) row
  float acc = 0.f;
#pragma unroll
  for (int dy = -1; dy <= 1; ++dy)
#pragma unroll
    for (int dx = -1; dx <= 1; ++dx) {
      const int y2 = yy + dy, x2 = xx + dx;
      if ((unsigned)y2 < (unsigned)WIMG && (unsigned)x2 < (unsigned)WIMG)
        acc += w[vc * 9 + (dy + 1) * 3 + (dx + 1)] * vb[y2 * WIMG + x2];
    }
  const float sc = gg[vc] * rsqrtf(vv[vc] + EPSV);
  const float bi = bb[vc] - mm[vc] * sc;
  atb[idx] += acc * sc + bi;
}

// ---------------- K3: MFMA attention (hi/lo split-precision QK^T) ----------------
__global__ __launch_bounds__(256) void k_attn(
    const u16* __restrict__ qbf, const u16* __restrict__ kbf,
    const u16* __restrict__ vtbf, float* __restrict__ attno)
{
  const int bh   = blockIdx.x & 31;
  const int qblk = blockIdx.x >> 5;          // 0..24
  const int b = bh >> 3, h = bh & 7;
  const int tid = threadIdx.x;
  const int lane = tid & 63, wid = tid >> 6;
  const int qloc = lane & 15, g = lane >> 4;

  __shared__ __align__(16) u16 Klds[KT][KLP];     // [key][hi0-7 lo0-7 pad]
  __shared__ __align__(16) u16 Vtlds[HDV][VTP];   // [d][key], padded rows

  const int qglob = qblk * 64 + wid * 16 + qloc;
  U16B qf;
  qf.u = *(const uint4*)&qbf[((size_t)bh * NPIX + qglob) * 16 + (g & 1) * 8];

  f32x4 c3 = {0.f, 0.f, 0.f, 0.f};
  float lsum = 0.f;
  const int idx0 = (((g & 1) << 5) | qloc) << 2;  // bpermute byte index
  const int idx1 = idx0 + 64;                     // +16 lanes
  const bool selA = (g < 2);
  const f32x4 zf = {0.f, 0.f, 0.f, 0.f};
  const int ksel = (g >> 1) * 8;                  // K-frag hi/lo select

  for (int kt = 0; kt < NPIX / KT; ++kt) {
    const int kb0 = kt * KT;
    __syncthreads();
    for (int i = tid; i < KT * 2; i += 256) {
      const int r = i >> 1, hf = (i & 1) * 8;
      *(uint4*)&Klds[r][hf] =
          *(const uint4*)&kbf[((size_t)bh * NPIX + kb0 + r) * 16 + hf];
    }
    for (int c = tid; c < HDV * (KT / 8); c += 256) {
      const int d = c / (KT / 8), n0 = (c % (KT / 8)) * 8;
      *(uint4*)&Vtlds[d][n0] =
          *(const uint4*)&vtbf[((size_t)bh * HDV + d) * NPIX + kb0 + n0];
    }
    __syncthreads();

    for (int ks = 0; ks < KT / 32; ++ks) {
      U16B kfA, kfB;
      kfA.u = *(const uint4*)&Klds[ks * 32 + qloc][ksel];
      kfB.u = *(const uint4*)&Klds[ks * 32 + 16 + qloc][ksel];
      f32x4 cA = __builtin_amdgcn_mfma_f32_16x16x32_bf16(kfA.v, qf.v, zf, 0, 0, 0);
      f32x4 cB = __builtin_amdgcn_mfma_f32_16x16x32_bf16(kfB.v, qf.v, zf, 0, 0, 0);

      const unsigned pkA0 = cvt_pk_bf16(__expf(cA[0]), __expf(cA[1]));
      const unsigned pkA1 = cvt_pk_bf16(__expf(cA[2]), __expf(cA[3]));
      const unsigned pkB0 = cvt_pk_bf16(__expf(cB[0]), __expf(cB[1]));
      const unsigned pkB1 = cvt_pk_bf16(__expf(cB[2]), __expf(cB[3]));

      const int a0 = __builtin_amdgcn_ds_bpermute(idx0, (int)pkA0);
      const int b0 = __builtin_amdgcn_ds_bpermute(idx0, (int)pkB0);
      const int a1 = __builtin_amdgcn_ds_bpermute(idx0, (int)pkA1);
      const int b1 = __builtin_amdgcn_ds_bpermute(idx0, (int)pkB1);
      const int a2 = __builtin_amdgcn_ds_bpermute(idx1, (int)pkA0);
      const int b2 = __builtin_amdgcn_ds_bpermute(idx1, (int)pkB0);
      const int a3 = __builtin_amdgcn_ds_bpermute(idx1, (int)pkA1);
      const int b3 = __builtin_amdgcn_ds_bpermute(idx1, (int)pkB1);
      U16B pf;
      pf.u.x = (unsigned)(selA ? a0 : b0);
      pf.u.y = (unsigned)(selA ? a1 : b1);
      pf.u.z = (unsigned)(selA ? a2 : b2);
      pf.u.w = (unsigned)(selA ? a3 : b3);

      lsum += __uint_as_float(pf.u.x << 16) + __uint_as_float(pf.u.x & 0xFFFF0000u)
            + __uint_as_float(pf.u.y << 16) + __uint_as_float(pf.u.y & 0xFFFF0000u)
            + __uint_as_float(pf.u.z << 16) + __uint_as_float(pf.u.z & 0xFFFF0000u)
            + __uint_as_float(pf.u.w << 16) + __uint_as_float(pf.u.w & 0xFFFF0000u);

      U16B vf4;
      vf4.u = *(const uint4*)&Vtlds[qloc][ks * 32 + g * 8];

      c3 = __builtin_amdgcn_mfma_f32_16x16x32_bf16(vf4.v, pf.v, c3, 0, 0, 0);
    }
  }

  lsum += __shfl_xor(lsum, 16);
  lsum += __shfl_xor(lsum, 32);
  const float rl = 1.f / lsum;

  float* ob = attno + ((size_t)b * CDIM + h * HDV) * NPIX + qblk * 64 + wid * 16 + qloc;
#pragma unroll
  for (int r = 0; r < 4; ++r)
    ob[(size_t)(g * 4 + r) * NPIX] = c3[r] * rl;
}

// ---------------- K4: y = BN(conv1x1(atb)) -> f32 out ----------------
// 2 output channels per block: 1792 blocks -> 28 waves/CU.
__global__ __launch_bounds__(256) void k_proj(
    const float* __restrict__ atb, const float* __restrict__ w,
    const float* __restrict__ gg, const float* __restrict__ bb,
    const float* __restrict__ mm, const float* __restrict__ vv,
    float* __restrict__ out)
{
  const int pblk = blockIdx.x % 7;
  const int ct   = (blockIdx.x / 7) % (CDIM / 2);
  const int b    = blockIdx.x / (7 * (CDIM / 2));
  const int tid  = threadIdx.x;

  __shared__ float wl[2][CDIM];
  wl[tid >> 7][tid & 127] = w[(ct * 2 + (tid >> 7)) * CDIM + (tid & 127)];
  __syncthreads();

  const int p = pblk * 256 + tid;
  if (p >= NPIX) return;

  const float* ab = atb + (size_t)b * CDIM * NPIX + p;
  float a0 = 0.f, a1 = 0.f;
#pragma unroll 8
  for (int ci = 0; ci < CDIM; ++ci) {
    const float xv = ab[(size_t)ci * NPIX];
    a0 += wl[0][ci] * xv;
    a1 += wl[1][ci] * xv;
  }
#pragma unroll
  for (int j = 0; j < 2; ++j) {
    const int c = ct * 2 + j;
    const float sc = gg[c] * rsqrtf(vv[c] + EPSV);
    const float bi = bb[c] - mm[c] * sc;
    out[((size_t)b * CDIM + c) * NPIX + p] = (j ? a1 : a0) * sc + bi;
  }
}

extern "C" void kernel_launch(void* const* d_in, const int* in_sizes, int n_in,
                              void* d_out, int out_size, void* d_ws, size_t ws_size,
                              hipStream_t stream)
{
  const float* x      = (const float*)d_in[0];
  const float* qkv_w  = (const float*)d_in[1];
  const float* qkv_g  = (const float*)d_in[2];
  const float* qkv_b  = (const float*)d_in[3];
  const float* qkv_m  = (const float*)d_in[4];
  const float* qkv_v  = (const float*)d_in[5];
  const float* pe_w   = (const float*)d_in[6];
  const float* pe_g   = (const float*)d_in[7];
  const float* pe_b   = (const float*)d_in[8];
  const float* pe_m   = (const float*)d_in[9];
  const float* pe_v   = (const float*)d_in[10];
  const float* proj_w = (const float*)d_in[11];
  const float* proj_g = (const float*)d_in[12];
  const float* proj_b = (const float*)d_in[13];
  const float* proj_m = (const float*)d_in[14];
  const float* proj_v = (const float*)d_in[15];

  float* ws   = (float*)d_ws;
  float* vf32 = ws;                                  // 819,200 f
  float* atb  = vf32 + (size_t)NB * CDIM * NPIX;     // 819,200 f
  u16*   qbf  = (u16*)(atb + (size_t)NB * CDIM * NPIX);        // 819,200 u16 (hi+lo)
  u16*   kbf  = qbf + (size_t)NB * NHEADS * NPIX * 16;         // 819,200 u16 (hi+lo)
  u16*   vtbf = kbf + (size_t)NB * NHEADS * NPIX * 16;         // 819,200 u16

  k_qkv<<<dim3(NB * (HCH / 8) * 7), 512, 0, stream>>>(
      x, qkv_w, qkv_g, qkv_b, qkv_m, qkv_v, vf32, qbf, kbf, vtbf);
  k_attn<<<dim3(NB * NHEADS * 25), 256, 0, stream>>>(qbf, kbf, vtbf, atb);
  k_peadd<<<dim3((NB * CDIM * NPIX + 255) / 256), 256, 0, stream>>>(
      vf32, pe_w, pe_g, pe_b, pe_m, pe_v, atb);
  k_proj<<<dim3(NB * (CDIM / 2) * 7), 256, 0, stream>>>(
      atb, proj_w, proj_g, proj_b, proj_m, proj_v, (float*)d_out);
}

// Round 8
// 145.690 us; speedup vs baseline: 1.8223x; 1.0512x over previous
//
#include <hip/hip_runtime.h>
#include <hip/hip_bf16.h>

#define NB 4
#define CDIM 128
#define NPIX 1600
#define WIMG 40
#define HCH 256
#define NHEADS 8
#define KDQ 8
#define HDV 16
#define EPSV 1e-3f
#define SCALEV 0.35355339059327373f
#define KT 320
#define KLP 24          // K-LDS row pad (u16) for 32B rows
#define VTP (KT + 8)

typedef unsigned short u16;
typedef float f32x4 __attribute__((ext_vector_type(4)));
typedef __bf16 bf16x8 __attribute__((ext_vector_type(8)));

union U16B { uint4 u; bf16x8 v; };

__device__ __forceinline__ u16 f2bf(float f) {   // RNE float->bf16 bits
  unsigned u = __float_as_uint(f);
  return (u16)((u + 0x7FFFu + ((u >> 16) & 1u)) >> 16);
}
__device__ __forceinline__ float bf2f(u16 b) {
  return __uint_as_float(((unsigned)b) << 16);
}
__device__ __forceinline__ unsigned cvt_pk_bf16(float lo, float hi) {
  unsigned r;
  asm("v_cvt_pk_bf16_f32 %0, %1, %2" : "=v"(r) : "v"(lo), "v"(hi));
  return r;
}

// ---------------- K1: qkv = BN(conv1x1(x)), split-K over ci ----------------
// 512 threads: half 0/1 each accumulate 64 ci, LDS-reduce, half 0 stores.
// Emits q/k as hi+lo bf16 split rows ([n][16]), v^T bf16 ([d][n]), fp32 v.
__global__ __launch_bounds__(512) void k_qkv(
    const float* __restrict__ x, const float* __restrict__ w,
    const float* __restrict__ gg, const float* __restrict__ bb,
    const float* __restrict__ mm, const float* __restrict__ vv,
    float* __restrict__ vf32, u16* __restrict__ qbf,
    u16* __restrict__ kbf, u16* __restrict__ vtbf)
{
  const int pblk = blockIdx.x % 7;
  const int ct   = (blockIdx.x / 7) % (HCH / 8);
  const int b    = blockIdx.x / (7 * (HCH / 8));
  const int tid  = threadIdx.x;
  const int half = tid >> 8;
  const int t    = tid & 255;

  __shared__ float wl[8][CDIM];
  __shared__ float red[256][8];
  for (int i = tid; i < 8 * CDIM; i += 512)
    wl[i >> 7][i & 127] = w[(ct * 8 + (i >> 7)) * CDIM + (i & 127)];
  __syncthreads();

  const int praw = pblk * 256 + t;
  const int p    = praw < NPIX ? praw : NPIX - 1;   // clamp (no early return)

  const float* xb = x + (size_t)b * CDIM * NPIX + p;
  float acc[8] = {0.f, 0.f, 0.f, 0.f, 0.f, 0.f, 0.f, 0.f};
  const int c0 = half * 64;
#pragma unroll 4
  for (int ci = c0; ci < c0 + 64; ++ci) {
    const float xv = xb[(size_t)ci * NPIX];
#pragma unroll
    for (int j = 0; j < 8; ++j) acc[j] += wl[j][ci] * xv;
  }

  if (half == 1) {
#pragma unroll
    for (int j = 0; j < 8; ++j) red[t][j] = acc[j];
  }
  __syncthreads();
  if (half == 1 || praw >= NPIX) return;
#pragma unroll
  for (int j = 0; j < 8; ++j) acc[j] += red[t][j];

  const int grp = ct & 3;   // 0=q(kd0-7) 1=k(kd0-7) 2=v(d0-7) 3=v(d8-15)
  const int h   = ct >> 2;
  float o[8];
#pragma unroll
  for (int j = 0; j < 8; ++j) {
    const int c = ct * 8 + j;
    const float sc = gg[c] * rsqrtf(vv[c] + EPSV);
    const float bi = bb[c] - mm[c] * sc;
    o[j] = acc[j] * sc + bi;
    if (grp == 0) o[j] *= SCALEV;
  }

  if (grp <= 1) {
    u16 hb[8], lb[8];
#pragma unroll
    for (int j = 0; j < 8; ++j) {
      hb[j] = f2bf(o[j]);
      lb[j] = f2bf(o[j] - bf2f(hb[j]));
    }
    uint4 H, L;
    H.x = hb[0] | ((unsigned)hb[1] << 16);
    H.y = hb[2] | ((unsigned)hb[3] << 16);
    H.z = hb[4] | ((unsigned)hb[5] << 16);
    H.w = hb[6] | ((unsigned)hb[7] << 16);
    L.x = lb[0] | ((unsigned)lb[1] << 16);
    L.y = lb[2] | ((unsigned)lb[3] << 16);
    L.z = lb[4] | ((unsigned)lb[5] << 16);
    L.w = lb[6] | ((unsigned)lb[7] << 16);
    u16* dst = (grp == 0) ? qbf : kbf;
    const size_t base = ((size_t)(b * NHEADS + h) * NPIX + p) * 16;
    *(uint4*)&dst[base]     = H;
    *(uint4*)&dst[base + 8] = L;
  } else {
    const int d0 = (grp == 2) ? 0 : 8;
#pragma unroll
    for (int j = 0; j < 8; ++j) {
      vtbf[((size_t)(b * NHEADS + h) * HDV + d0 + j) * NPIX + p] = f2bf(o[j]);
      vf32[((size_t)b * CDIM + h * HDV + d0 + j) * NPIX + p] = o[j];
    }
  }
}

// ---------------- K2: MFMA attention + fused pe epilogue ----------------
// 512 thr = 8 waves: wave (qw = wid&3, kh = wid>>2) handles query sub-tile qw
// (16 queries) and key-half kh of each staged KT tile. Cross-wave partial
// (c3, lsum) reduction through LDS; kh=0 waves run the epilogue:
// out = attn/lsum + BN(dwconv3x3(v)) written once to atb.
__global__ __launch_bounds__(512) void k_attn(
    const u16* __restrict__ qbf, const u16* __restrict__ kbf,
    const u16* __restrict__ vtbf, const float* __restrict__ vf32,
    const float* __restrict__ pw, const float* __restrict__ pg,
    const float* __restrict__ pbb, const float* __restrict__ pm,
    const float* __restrict__ pv, float* __restrict__ atb)
{
  const int bh   = blockIdx.x & 31;
  const int qblk = blockIdx.x >> 5;          // 0..24
  const int b = bh >> 3, h = bh & 7;
  const int tid = threadIdx.x;
  const int lane = tid & 63, wid = tid >> 6;
  const int qw = wid & 3, kh = wid >> 2;
  const int qloc = lane & 15, g = lane >> 4;

  __shared__ __align__(16) u16 Klds[KT][KLP];     // [key][hi0-7 lo0-7 pad]
  __shared__ __align__(16) u16 Vtlds[HDV][VTP];   // [d][key], padded rows
  __shared__ float red[256][6];                   // kh=1 partials: c3[0..3], lsum

  const int qglob = qblk * 64 + qw * 16 + qloc;
  U16B qf;
  qf.u = *(const uint4*)&qbf[((size_t)bh * NPIX + qglob) * 16 + (g & 1) * 8];

  f32x4 c3 = {0.f, 0.f, 0.f, 0.f};
  float lsum = 0.f;
  const int idx0 = (((g & 1) << 5) | qloc) << 2;  // bpermute byte index
  const int idx1 = idx0 + 64;                     // +16 lanes
  const bool selA = (g < 2);
  const f32x4 zf = {0.f, 0.f, 0.f, 0.f};
  const int ksel = (g >> 1) * 8;                  // K-frag hi/lo select

  for (int kt = 0; kt < NPIX / KT; ++kt) {
    const int kb0 = kt * KT;
    __syncthreads();
    for (int i = tid; i < KT * 2; i += 512) {
      const int r = i >> 1, hf = (i & 1) * 8;
      *(uint4*)&Klds[r][hf] =
          *(const uint4*)&kbf[((size_t)bh * NPIX + kb0 + r) * 16 + hf];
    }
    for (int c = tid; c < HDV * (KT / 8); c += 512) {
      const int d = c / (KT / 8), n0 = (c % (KT / 8)) * 8;
      *(uint4*)&Vtlds[d][n0] =
          *(const uint4*)&vtbf[((size_t)bh * HDV + d) * NPIX + kb0 + n0];
    }
    __syncthreads();

    for (int ks = kh * 5; ks < kh * 5 + 5; ++ks) {
      U16B kfA, kfB;
      kfA.u = *(const uint4*)&Klds[ks * 32 + qloc][ksel];
      kfB.u = *(const uint4*)&Klds[ks * 32 + 16 + qloc][ksel];
      f32x4 cA = __builtin_amdgcn_mfma_f32_16x16x32_bf16(kfA.v, qf.v, zf, 0, 0, 0);
      f32x4 cB = __builtin_amdgcn_mfma_f32_16x16x32_bf16(kfB.v, qf.v, zf, 0, 0, 0);

      const unsigned pkA0 = cvt_pk_bf16(__expf(cA[0]), __expf(cA[1]));
      const unsigned pkA1 = cvt_pk_bf16(__expf(cA[2]), __expf(cA[3]));
      const unsigned pkB0 = cvt_pk_bf16(__expf(cB[0]), __expf(cB[1]));
      const unsigned pkB1 = cvt_pk_bf16(__expf(cB[2]), __expf(cB[3]));

      const int a0 = __builtin_amdgcn_ds_bpermute(idx0, (int)pkA0);
      const int b0 = __builtin_amdgcn_ds_bpermute(idx0, (int)pkB0);
      const int a1 = __builtin_amdgcn_ds_bpermute(idx0, (int)pkA1);
      const int b1 = __builtin_amdgcn_ds_bpermute(idx0, (int)pkB1);
      const int a2 = __builtin_amdgcn_ds_bpermute(idx1, (int)pkA0);
      const int b2 = __builtin_amdgcn_ds_bpermute(idx1, (int)pkB0);
      const int a3 = __builtin_amdgcn_ds_bpermute(idx1, (int)pkA1);
      const int b3 = __builtin_amdgcn_ds_bpermute(idx1, (int)pkB1);
      U16B pf;
      pf.u.x = (unsigned)(selA ? a0 : b0);
      pf.u.y = (unsigned)(selA ? a1 : b1);
      pf.u.z = (unsigned)(selA ? a2 : b2);
      pf.u.w = (unsigned)(selA ? a3 : b3);

      lsum += __uint_as_float(pf.u.x << 16) + __uint_as_float(pf.u.x & 0xFFFF0000u)
            + __uint_as_float(pf.u.y << 16) + __uint_as_float(pf.u.y & 0xFFFF0000u)
            + __uint_as_float(pf.u.z << 16) + __uint_as_float(pf.u.z & 0xFFFF0000u)
            + __uint_as_float(pf.u.w << 16) + __uint_as_float(pf.u.w & 0xFFFF0000u);

      U16B vf4;
      vf4.u = *(const uint4*)&Vtlds[qloc][ks * 32 + g * 8];

      c3 = __builtin_amdgcn_mfma_f32_16x16x32_bf16(vf4.v, pf.v, c3, 0, 0, 0);
    }
  }

  // combine key halves across wave pairs (kh=1 -> kh=0)
  if (kh == 1) {
    const int rr = qw * 64 + lane;
    red[rr][0] = c3[0]; red[rr][1] = c3[1];
    red[rr][2] = c3[2]; red[rr][3] = c3[3];
    red[rr][4] = lsum;
  }
  __syncthreads();
  if (kh == 1) return;
  {
    const int rr = qw * 64 + lane;
    c3[0] += red[rr][0]; c3[1] += red[rr][1];
    c3[2] += red[rr][2]; c3[3] += red[rr][3];
    lsum  += red[rr][4];
  }

  lsum += __shfl_xor(lsum, 16);
  lsum += __shfl_xor(lsum, 32);
  const float rl = 1.f / lsum;

  // Epilogue: out[d][p] = c3[r]*rl + BN(dwconv3x3(v))[c=h*16+d][p]
  const int p  = qblk * 64 + qw * 16 + qloc;
  const int yy = p / WIMG, xx = p % WIMG;
  const float* vb = vf32 + ((size_t)b * CDIM + h * HDV) * NPIX;
  float* ob = atb + ((size_t)b * CDIM + h * HDV) * NPIX + p;
#pragma unroll
  for (int r = 0; r < 4; ++r) {
    const int d = g * 4 + r;
    const int c = h * HDV + d;
    float acc = 0.f;
#pragma unroll
    for (int dy = -1; dy <= 1; ++dy)
#pragma unroll
      for (int dx = -1; dx <= 1; ++dx) {
        const int y2 = yy + dy, x2 = xx + dx;
        if ((unsigned)y2 < (unsigned)WIMG && (unsigned)x2 < (unsigned)WIMG)
          acc += pw[c * 9 + (dy + 1) * 3 + (dx + 1)] * vb[(size_t)d * NPIX + y2 * WIMG + x2];
      }
    const float sc = pg[c] * rsqrtf(pv[c] + EPSV);
    const float bi = pbb[c] - pm[c] * sc;
    ob[(size_t)d * NPIX] = c3[r] * rl + acc * sc + bi;
  }
}

// ---------------- K3: y = BN(conv1x1(atb)) -> f32 out ----------------
// 2 output channels per block: 1792 blocks -> 28 waves/CU.
__global__ __launch_bounds__(256) void k_proj(
    const float* __restrict__ atb, const float* __restrict__ w,
    const float* __restrict__ gg, const float* __restrict__ bb,
    const float* __restrict__ mm, const float* __restrict__ vv,
    float* __restrict__ out)
{
  const int pblk = blockIdx.x % 7;
  const int ct   = (blockIdx.x / 7) % (CDIM / 2);
  const int b    = blockIdx.x / (7 * (CDIM / 2));
  const int tid  = threadIdx.x;

  __shared__ float wl[2][CDIM];
  wl[tid >> 7][tid & 127] = w[(ct * 2 + (tid >> 7)) * CDIM + (tid & 127)];
  __syncthreads();

  const int p = pblk * 256 + tid;
  if (p >= NPIX) return;

  const float* ab = atb + (size_t)b * CDIM * NPIX + p;
  float a0 = 0.f, a1 = 0.f;
#pragma unroll 8
  for (int ci = 0; ci < CDIM; ++ci) {
    const float xv = ab[(size_t)ci * NPIX];
    a0 += wl[0][ci] * xv;
    a1 += wl[1][ci] * xv;
  }
#pragma unroll
  for (int j = 0; j < 2; ++j) {
    const int c = ct * 2 + j;
    const float sc = gg[c] * rsqrtf(vv[c] + EPSV);
    const float bi = bb[c] - mm[c] * sc;
    out[((size_t)b * CDIM + c) * NPIX + p] = (j ? a1 : a0) * sc + bi;
  }
}

extern "C" void kernel_launch(void* const* d_in, const int* in_sizes, int n_in,
                              void* d_out, int out_size, void* d_ws, size_t ws_size,
                              hipStream_t stream)
{
  const float* x      = (const float*)d_in[0];
  const float* qkv_w  = (const float*)d_in[1];
  const float* qkv_g  = (const float*)d_in[2];
  const float* qkv_b  = (const float*)d_in[3];
  const float* qkv_m  = (const float*)d_in[4];
  const float* qkv_v  = (const float*)d_in[5];
  const float* pe_w   = (const float*)d_in[6];
  const float* pe_g   = (const float*)d_in[7];
  const float* pe_b   = (const float*)d_in[8];
  const float* pe_m   = (const float*)d_in[9];
  const float* pe_v   = (const float*)d_in[10];
  const float* proj_w = (const float*)d_in[11];
  const float* proj_g = (const float*)d_in[12];
  const float* proj_b = (const float*)d_in[13];
  const float* proj_m = (const float*)d_in[14];
  const float* proj_v = (const float*)d_in[15];

  float* ws   = (float*)d_ws;
  float* vf32 = ws;                                  // 819,200 f
  float* atb  = vf32 + (size_t)NB * CDIM * NPIX;     // 819,200 f
  u16*   qbf  = (u16*)(atb + (size_t)NB * CDIM * NPIX);        // 819,200 u16 (hi+lo)
  u16*   kbf  = qbf + (size_t)NB * NHEADS * NPIX * 16;         // 819,200 u16 (hi+lo)
  u16*   vtbf = kbf + (size_t)NB * NHEADS * NPIX * 16;         // 819,200 u16

  k_qkv<<<dim3(NB * (HCH / 8) * 7), 512, 0, stream>>>(
      x, qkv_w, qkv_g, qkv_b, qkv_m, qkv_v, vf32, qbf, kbf, vtbf);
  k_attn<<<dim3(NB * NHEADS * 25), 512, 0, stream>>>(
      qbf, kbf, vtbf, vf32, pe_w, pe_g, pe_b, pe_m, pe_v, atb);
  k_proj<<<dim3(NB * (CDIM / 2) * 7), 256, 0, stream>>>(
      atb, proj_w, proj_g, proj_b, proj_m, proj_v, (float*)d_out);
}